// Round 7
// baseline (1404.197 us; speedup 1.0000x reference)
//
#include <hip/hip_runtime.h>
#include <cstdint>
#include <math.h>

#define B_ 4
#define T_ 2048
#define C_ 512
#define H_ 8
#define HD_ 64
#define TOPK_ 32
#define ROWS_ (B_*H_*T_)   /* 65536 */
#define BT_ (B_*T_)        /* 8192 */

// ---------------- QKV projection GEMM: (8192x512)@(512x512) ------------------------
// Q: [bh][tok][64] fp32. K: written TRANSPOSED as Kt[bh][d][2048] fp32 (so the fused
// scores kernel streams it fully coalesced). V: [bh][tok][64] fp32.
__global__ __launch_bounds__(256) void qkv_kernel(
    const float* __restrict__ x,
    const float* __restrict__ Wq, const float* __restrict__ bq,
    const float* __restrict__ Wk, const float* __restrict__ bk,
    const float* __restrict__ Wv, const float* __restrict__ bv,
    float* __restrict__ Q, float* __restrict__ Kt, float* __restrict__ V)
{
    const int which = blockIdx.z;
    const float* W    = (which == 0) ? Wq : (which == 1) ? Wk : Wv;
    const float* bias = (which == 0) ? bq : (which == 1) ? bk : bv;

    const int m0 = blockIdx.y * 128;
    const int n0 = blockIdx.x * 128;
    __shared__ float As[16][128];   // [k][m] transposed
    __shared__ float Bs[16][128];   // [k][n]
    float acc[8][8] = {};
    const int tid = threadIdx.x;
    const int tx = tid & 15, ty = tid >> 4;

    for (int k0 = 0; k0 < C_; k0 += 16) {
        #pragma unroll
        for (int i = 0; i < 2; ++i) {
            int t = tid + i * 256;           // 0..511
            int m  = t >> 2;                 // 0..127
            int kq = (t & 3) << 2;           // 0,4,8,12
            float4 a4 = *(const float4*)(x + (size_t)(m0 + m) * C_ + k0 + kq);
            As[kq + 0][m] = a4.x; As[kq + 1][m] = a4.y;
            As[kq + 2][m] = a4.z; As[kq + 3][m] = a4.w;
            int kk2 = t >> 5;                // 0..15
            int nq  = (t & 31) << 2;         // 0..124
            *(float4*)&Bs[kk2][nq] = *(const float4*)(W + (size_t)(k0 + kk2) * C_ + n0 + nq);
        }
        __syncthreads();
        #pragma unroll
        for (int k = 0; k < 16; ++k) {
            float a[8], b[8];
            *(float4*)&a[0] = *(const float4*)&As[k][ty * 8];
            *(float4*)&a[4] = *(const float4*)&As[k][ty * 8 + 4];
            *(float4*)&b[0] = *(const float4*)&Bs[k][tx * 8];
            *(float4*)&b[4] = *(const float4*)&Bs[k][tx * 8 + 4];
            #pragma unroll
            for (int i = 0; i < 8; ++i)
                #pragma unroll
                for (int j = 0; j < 8; ++j)
                    acc[i][j] += a[i] * b[j];
        }
        __syncthreads();
    }

    const int bb = m0 >> 11;                 // batch index (m0 constant per block)
    const int t0 = (m0 & (T_ - 1)) + ty * 8; // token of acc row i=0

    if (which == 1) {
        // K transposed out: Kt[(bb*8+h)*64 + d][t]
        #pragma unroll
        for (int jj = 0; jj < 8; ++jj) {
            int n = n0 + tx * 8 + jj;
            int h = n >> 6, d = n & 63;
            float bv_ = bias[n];
            float* dst = Kt + (((size_t)(bb * H_ + h) * HD_ + d) << 11) + t0;
            float4 lo, hi;
            lo.x = acc[0][jj] + bv_; lo.y = acc[1][jj] + bv_;
            lo.z = acc[2][jj] + bv_; lo.w = acc[3][jj] + bv_;
            hi.x = acc[4][jj] + bv_; hi.y = acc[5][jj] + bv_;
            hi.z = acc[6][jj] + bv_; hi.w = acc[7][jj] + bv_;
            *(float4*)(dst)     = lo;
            *(float4*)(dst + 4) = hi;
        }
    } else {
        float* out = (which == 0) ? Q : V;
        #pragma unroll
        for (int i = 0; i < 8; ++i) {
            int t = t0 + i;
            #pragma unroll
            for (int j = 0; j < 8; j += 4) {
                int n = n0 + tx * 8 + j;
                int h = n >> 6, d = n & 63;
                float4 v4;
                v4.x = acc[i][j + 0] + bias[n + 0];
                v4.y = acc[i][j + 1] + bias[n + 1];
                v4.z = acc[i][j + 2] + bias[n + 2];
                v4.w = acc[i][j + 3] + bias[n + 3];
                *(float4*)(out + (((size_t)(bb * H_ + h) * T_ + t) << 6) + d) = v4;
            }
        }
    }
}

// ---------------- fused: fp32 scores + exact top-32 (linear-bucket select) ----------
// Block: 4 waves, 8 query rows x 2048 key cols. Scores in VGPRs (64/lane):
// lane holds rows 0..7 (all), cols = wave*512 + (e>>2)*256 + lane*4 + (e&3).
// Selection: one 256-bucket linear histogram over [rowmin,rowmax]; bucket ids are
// PACKED into registers during the histogram sweep (collect unpacks with shift+mask,
// no recompute). Boundary bucket via suffix scan, exact (value desc, col asc) ranking
// of the few boundary candidates, canonical reorder -> bitwise deterministic output.
__global__ __launch_bounds__(256, 4) void fused_attn_topk(
    const float* __restrict__ Q, const float* __restrict__ Kt,
    float* __restrict__ S, float* __restrict__ probs_c, int* __restrict__ idx_c)
{
    const int tid  = threadIdx.x;
    const int wave = tid >> 6, lane = tid & 63;
    const int m0 = blockIdx.x * 8;
    const int bh = blockIdx.y;

    __shared__ float Qs[64][12];             // [d][row], padded to 48B stride
    __shared__ int   hist[8][257];           // padded: bank(r,b) = (r+b)&31
    __shared__ float wlo[4][8], whi[4][8];
    __shared__ float rowlo[8], rowinv[8];
    __shared__ int   bb_s[8], G_s[8], gcnt[8], cin[8];
    __shared__ float selv[8][32], selv2[8][32], candv[8][64];
    __shared__ int   seli[8][32], seli2[8][32], candc[8][64];

    // stage Q tile (8 tokens x 64 d) transposed; zero hist; init counters
    if (tid < 128) {
        int tok = tid >> 4;                  // 0..7
        int dq  = (tid & 15) << 2;           // 0,4,..,60
        float4 q4 = *(const float4*)(Q + (((size_t)bh * T_ + m0 + tok) << 6) + dq);
        Qs[dq + 0][tok] = q4.x; Qs[dq + 1][tok] = q4.y;
        Qs[dq + 2][tok] = q4.z; Qs[dq + 3][tok] = q4.w;
    }
    for (int idx = tid; idx < 8 * 257; idx += 256) ((int*)hist)[idx] = 0;
    if (tid < 8) { gcnt[tid] = 0; cin[tid] = 0; }
    __syncthreads();

    // ---- phase A: fp32 scores, register-resident ----
    float acc[8][8];
    #pragma unroll
    for (int r = 0; r < 8; ++r)
        #pragma unroll
        for (int e = 0; e < 8; ++e) acc[r][e] = 0.f;

    const float* ktp = Kt + ((size_t)bh * HD_ << 11) + wave * 512 + lane * 4;
    #pragma unroll 4
    for (int d = 0; d < 64; ++d) {
        float4 k0 = *(const float4*)(ktp);
        float4 k1 = *(const float4*)(ktp + 256);
        ktp += 2048;
        float qv[8];
        *(float4*)&qv[0] = *(const float4*)&Qs[d][0];
        *(float4*)&qv[4] = *(const float4*)&Qs[d][4];
        #pragma unroll
        for (int r = 0; r < 8; ++r) {
            acc[r][0] = fmaf(qv[r], k0.x, acc[r][0]);
            acc[r][1] = fmaf(qv[r], k0.y, acc[r][1]);
            acc[r][2] = fmaf(qv[r], k0.z, acc[r][2]);
            acc[r][3] = fmaf(qv[r], k0.w, acc[r][3]);
            acc[r][4] = fmaf(qv[r], k1.x, acc[r][4]);
            acc[r][5] = fmaf(qv[r], k1.y, acc[r][5]);
            acc[r][6] = fmaf(qv[r], k1.z, acc[r][6]);
            acc[r][7] = fmaf(qv[r], k1.w, acc[r][7]);
        }
    }
    #pragma unroll
    for (int r = 0; r < 8; ++r)
        #pragma unroll
        for (int e = 0; e < 8; ++e) acc[r][e] *= 0.125f;   // exact pow2 scale

    // ---- per-row min/max (register shuffle reduce, no atomics) ----
    float mn[8], mx[8];
    #pragma unroll
    for (int r = 0; r < 8; ++r) {
        mn[r] = acc[r][0]; mx[r] = acc[r][0];
        #pragma unroll
        for (int e = 1; e < 8; ++e) {
            mn[r] = fminf(mn[r], acc[r][e]);
            mx[r] = fmaxf(mx[r], acc[r][e]);
        }
    }
    #pragma unroll
    for (int off = 32; off >= 1; off >>= 1) {
        #pragma unroll
        for (int r = 0; r < 8; ++r) {
            mn[r] = fminf(mn[r], __shfl_xor(mn[r], off));
            mx[r] = fmaxf(mx[r], __shfl_xor(mx[r], off));
        }
    }
    if (lane == 0) {
        #pragma unroll
        for (int r = 0; r < 8; ++r) { wlo[wave][r] = mn[r]; whi[wave][r] = mx[r]; }
    }
    __syncthreads();
    if (tid < 8) {
        float lo = wlo[0][tid], hi = whi[0][tid];
        #pragma unroll
        for (int w = 1; w < 4; ++w) {
            lo = fminf(lo, wlo[w][tid]);
            hi = fmaxf(hi, whi[w][tid]);
        }
        float range = hi - lo;
        rowlo[tid]  = lo;
        rowinv[tid] = (range > 0.f) ? (256.0f / range) : 0.f;
    }
    __syncthreads();

    // ---- one-pass 256-bucket histogram; pack bucket ids into registers ----
    float lo_r[8], inv_r[8];
    #pragma unroll
    for (int r = 0; r < 8; ++r) { lo_r[r] = rowlo[r]; inv_r[r] = rowinv[r]; }
    unsigned int bpack[16];                  // [r*2 + (e>>2)], 4x 8-bit buckets each
    #pragma unroll
    for (int r = 0; r < 8; ++r) {
        #pragma unroll
        for (int h = 0; h < 2; ++h) {
            unsigned int pk = 0;
            #pragma unroll
            for (int j = 0; j < 4; ++j) {
                int b = (int)((acc[r][h * 4 + j] - lo_r[r]) * inv_r[r]);
                b = b < 0 ? 0 : (b > 255 ? 255 : b);
                pk |= (unsigned int)b << (8 * j);
                atomicAdd(&hist[r][b], 1);
            }
            bpack[r * 2 + h] = pk;
        }
    }
    __syncthreads();

    // ---- boundary bucket per row (suffix scan); wave w handles rows 2w,2w+1 ----
    #pragma unroll
    for (int rr = 0; rr < 2; ++rr) {
        const int row = wave * 2 + rr;
        int h0 = hist[row][lane * 4 + 0], h1 = hist[row][lane * 4 + 1];
        int h2 = hist[row][lane * 4 + 2], h3 = hist[row][lane * 4 + 3];
        int lsum = h0 + h1 + h2 + h3;
        int suf = lsum;
        #pragma unroll
        for (int off = 1; off < 64; off <<= 1) {
            int v = __shfl_down(suf, off);
            if (lane + off < 64) suf += v;
        }
        int a3 = suf - lsum;          // elems in strictly higher buckets
        int a2 = a3 + h3;
        int a1 = a2 + h2;
        int a0 = a1 + h1;
        if (a3 < TOPK_ && TOPK_ <= a3 + h3) { bb_s[row] = lane * 4 + 3; G_s[row] = a3; }
        if (a2 < TOPK_ && TOPK_ <= a2 + h2) { bb_s[row] = lane * 4 + 2; G_s[row] = a2; }
        if (a1 < TOPK_ && TOPK_ <= a1 + h1) { bb_s[row] = lane * 4 + 1; G_s[row] = a1; }
        if (a0 < TOPK_ && TOPK_ <= a0 + h0) { bb_s[row] = lane * 4 + 0; G_s[row] = a0; }
    }
    __syncthreads();

    // ---- collect: definite winners (b > boundary) + boundary candidates ----
    int bb_r[8];
    #pragma unroll
    for (int r = 0; r < 8; ++r) bb_r[r] = bb_s[r];
    const int colb = wave * 512 + lane * 4;
    #pragma unroll
    for (int r = 0; r < 8; ++r) {
        #pragma unroll
        for (int e = 0; e < 8; ++e) {
            int b = (int)((bpack[r * 2 + (e >> 2)] >> (8 * (e & 3))) & 255u);
            int col = colb + ((e >> 2) << 8) + (e & 3);
            if (b > bb_r[r]) {
                int p = atomicAdd(&gcnt[r], 1);
                selv[r][p] = acc[r][e];
                seli[r][p] = col;
            } else if (b == bb_r[r]) {
                int q = atomicAdd(&cin[r], 1);
                if (q < 64) { candv[r][q] = acc[r][e]; candc[r][q] = col; }
            }
        }
    }
    __syncthreads();

    // ---- exact rank of boundary candidates (value desc, col asc) ----
    // Deterministic: rank is a function of the candidate SET, not slot order.
    #pragma unroll
    for (int base = 0; base < 512; base += 256) {
        int idx = base + tid;
        int r = idx >> 6, j = idx & 63;
        int cnt = cin[r]; if (cnt > 64) cnt = 64;
        int G = G_s[r], need = TOPK_ - G;
        if (j < cnt) {
            float v = candv[r][j]; int c = candc[r][j];
            int rank = 0;
            for (int s = 0; s < cnt; ++s) {
                float vo = candv[r][s]; int co = candc[r][s];
                rank += (vo > v) || (vo == v && co < c);
            }
            if (rank < need) { selv[r][G + rank] = v; seli[r][G + rank] = c; }
        }
    }
    __syncthreads();

    // ---- canonical rank-reorder of the 32 (value desc, col asc) ----
    {
        int row = tid >> 5, slot = tid & 31;
        float v = selv[row][slot];
        int   c = seli[row][slot];
        int rank = 0;
        #pragma unroll
        for (int s = 0; s < 32; ++s) {
            float vo = selv[row][s]; int co = seli[row][s];
            rank += (vo > v) || (vo == v && co < c);
        }
        selv2[row][rank] = v;
        seli2[row][rank] = c;
    }
    __syncthreads();

    // ---- softmax over 32 per row + compact outputs ----
    {
        int row = tid >> 5, slot = tid & 31;
        float v = selv2[row][slot];
        float mxv = v;
        #pragma unroll
        for (int off = 16; off >= 1; off >>= 1) mxv = fmaxf(mxv, __shfl_xor(mxv, off, 32));
        float ex = expf(v - mxv);
        float sm = ex;
        #pragma unroll
        for (int off = 16; off >= 1; off >>= 1) sm += __shfl_xor(sm, off, 32);
        float p = ex / sm;
        selv2[row][slot] = p;
        size_t grow = (size_t)(bh * T_ + m0 + row) * 32 + slot;
        probs_c[grow] = p;
        idx_c[grow]   = seli2[row][slot];
    }
    __syncthreads();

    // ---- dense output: zero 8x2048 then scatter 8x32 probs ----
    float* Sb = S + (size_t)bh * T_ * T_ + (size_t)m0 * T_;
    float4 z4 = {0.f, 0.f, 0.f, 0.f};
    #pragma unroll
    for (int i = 0; i < 16; ++i) ((float4*)Sb)[tid + i * 256] = z4;
    __syncthreads();
    {
        int row = tid >> 5, slot = tid & 31;
        Sb[(size_t)row * T_ + seli2[row][slot]] = selv2[row][slot];
    }
}

// ---------------- sparse context: ctx[b,t,h*64+d] = sum_j p_j * V[bh, idx_j, d] ----
__global__ __launch_bounds__(256) void context_kernel(
    const float* __restrict__ V, const float* __restrict__ probs_c,
    const int* __restrict__ idx_c, float* __restrict__ ctx)
{
    const int wid = blockIdx.x * 4 + (threadIdx.x >> 6);
    const int lane = threadIdx.x & 63;
    const int bh = wid >> 11, t = wid & (T_ - 1);
    const float* Vb = V + ((size_t)bh * T_ << 6);
    const float* pr = probs_c + (size_t)wid * 32;
    const int* ir = idx_c + (size_t)wid * 32;
    float acc = 0.f;
    #pragma unroll 8
    for (int j = 0; j < 32; ++j) {
        float p = pr[j];
        int ix = ir[j];
        acc += p * Vb[((size_t)ix << 6) + lane];
    }
    const int b = bh >> 3, h = bh & 7;
    ctx[(size_t)(b * T_ + t) * C_ + h * 64 + lane] = acc;
}

// ---------------- Wo GEMM + bias -> analog (row-major) -----------------------------
__global__ __launch_bounds__(256) void wo_kernel(
    const float* __restrict__ A, const float* __restrict__ W,
    const float* __restrict__ bias, float* __restrict__ out)
{
    const int m0 = blockIdx.y * 128;
    const int n0 = blockIdx.x * 128;
    __shared__ float As[16][128];
    __shared__ float Bs[16][128];
    float acc[8][8] = {};
    const int tid = threadIdx.x;
    const int tx = tid & 15, ty = tid >> 4;

    for (int k0 = 0; k0 < C_; k0 += 16) {
        #pragma unroll
        for (int i = 0; i < 2; ++i) {
            int t = tid + i * 256;
            int m  = t >> 2;
            int kq = (t & 3) << 2;
            float4 a4 = *(const float4*)(A + (size_t)(m0 + m) * C_ + k0 + kq);
            As[kq + 0][m] = a4.x; As[kq + 1][m] = a4.y;
            As[kq + 2][m] = a4.z; As[kq + 3][m] = a4.w;
            int kk2 = t >> 5;
            int nq  = (t & 31) << 2;
            *(float4*)&Bs[kk2][nq] = *(const float4*)(W + (size_t)(k0 + kk2) * C_ + n0 + nq);
        }
        __syncthreads();
        #pragma unroll
        for (int k = 0; k < 16; ++k) {
            float a[8], b[8];
            *(float4*)&a[0] = *(const float4*)&As[k][ty * 8];
            *(float4*)&a[4] = *(const float4*)&As[k][ty * 8 + 4];
            *(float4*)&b[0] = *(const float4*)&Bs[k][tx * 8];
            *(float4*)&b[4] = *(const float4*)&Bs[k][tx * 8 + 4];
            #pragma unroll
            for (int i = 0; i < 8; ++i)
                #pragma unroll
                for (int j = 0; j < 8; ++j)
                    acc[i][j] += a[i] * b[j];
        }
        __syncthreads();
    }
    #pragma unroll
    for (int i = 0; i < 8; ++i) {
        int r = m0 + ty * 8 + i;
        #pragma unroll
        for (int j = 0; j < 8; j += 4) {
            int n = n0 + tx * 8 + j;
            float4 v4;
            v4.x = acc[i][j + 0] + bias[n + 0];
            v4.y = acc[i][j + 1] + bias[n + 1];
            v4.z = acc[i][j + 2] + bias[n + 2];
            v4.w = acc[i][j + 3] + bias[n + 3];
            *(float4*)(out + (size_t)r * C_ + n) = v4;
        }
    }
}

// ---------------- LayerNorm in place: one wave per row of 512 ----------------------
__global__ __launch_bounds__(256) void ln_kernel(
    float* __restrict__ a, const float* __restrict__ gamma, const float* __restrict__ beta)
{
    const int row = blockIdx.x * 4 + (threadIdx.x >> 6);
    const int lane = threadIdx.x & 63;
    float* ar = a + (size_t)row * C_;
    float x[8];
    *(float4*)&x[0] = *(const float4*)(ar + lane * 8);
    *(float4*)&x[4] = *(const float4*)(ar + lane * 8 + 4);
    float s = 0.f;
    #pragma unroll
    for (int i = 0; i < 8; ++i) s += x[i];
    #pragma unroll
    for (int off = 32; off >= 1; off >>= 1) s += __shfl_xor(s, off);
    float mu = s * (1.0f / C_);
    float vs = 0.f;
    #pragma unroll
    for (int i = 0; i < 8; ++i) { float d = x[i] - mu; vs += d * d; }
    #pragma unroll
    for (int off = 32; off >= 1; off >>= 1) vs += __shfl_xor(vs, off);
    float rs = rsqrtf(vs * (1.0f / C_) + 1e-5f);
    float g[8], bt[8];
    *(float4*)&g[0]  = *(const float4*)(gamma + lane * 8);
    *(float4*)&g[4]  = *(const float4*)(gamma + lane * 8 + 4);
    *(float4*)&bt[0] = *(const float4*)(beta + lane * 8);
    *(float4*)&bt[4] = *(const float4*)(beta + lane * 8 + 4);
    #pragma unroll
    for (int i = 0; i < 8; ++i) x[i] = (x[i] - mu) * rs * g[i] + bt[i];
    *(float4*)(ar + lane * 8)     = *(float4*)&x[0];
    *(float4*)(ar + lane * 8 + 4) = *(float4*)&x[4];
}

// ---------------- adaptive LIF scan, in place (analog -> spikes) -------------------
#define LIF_BATCH 32
__global__ __launch_bounds__(64) void lif_kernel(float* __restrict__ a)
{
    const int wid = blockIdx.x;                 // 0..31
    const int b = wid >> 3;
    const int c = ((wid & 7) << 6) | threadIdx.x;
    float* base = a + (size_t)b * T_ * C_ + c;

    float xb[2][LIF_BATCH];
    #pragma unroll
    for (int j = 0; j < LIF_BATCH; ++j)
        xb[0][j] = base[(size_t)j * C_];

    float vmem = 0.f, adapt = 0.f;
    #pragma unroll 1
    for (int t0 = 0; t0 < T_; t0 += LIF_BATCH) {
        const int cur = (t0 / LIF_BATCH) & 1;
        if (t0 + LIF_BATCH < T_) {
            #pragma unroll
            for (int j = 0; j < LIF_BATCH; ++j)
                xb[cur ^ 1][j] = base[(size_t)(t0 + LIF_BATCH + j) * C_];
        }
        #pragma unroll
        for (int j = 0; j < LIF_BATCH; ++j) {
            float x = xb[cur][j];
            vmem = fmaf(0.9f, vmem, x);
            float th = fmaf(0.1f, adapt, 1.0f);
            float s = (vmem - th) > 0.f ? 1.f : 0.f;
            vmem -= s * th;
            adapt = fmaf(0.9f, adapt, s);
            xb[cur][j] = s;
        }
        #pragma unroll
        for (int j = 0; j < LIF_BATCH; ++j)
            base[(size_t)(t0 + j) * C_] = xb[cur][j];
    }
}

extern "C" void kernel_launch(void* const* d_in, const int* in_sizes, int n_in,
                              void* d_out, int out_size, void* d_ws, size_t ws_size,
                              hipStream_t stream)
{
    const float* x     = (const float*)d_in[0];
    const float* Wq    = (const float*)d_in[1];
    const float* bq    = (const float*)d_in[2];
    const float* Wk    = (const float*)d_in[3];
    const float* bk    = (const float*)d_in[4];
    const float* Wv    = (const float*)d_in[5];
    const float* bv    = (const float*)d_in[6];
    const float* Wo    = (const float*)d_in[7];
    const float* bo    = (const float*)d_in[8];
    const float* gamma = (const float*)d_in[9];
    const float* beta  = (const float*)d_in[10];

    float* out    = (float*)d_out;
    float* spikes = out;                                   // B*T*C (also analog scratch)
    float* probs  = out + (size_t)B_ * T_ * C_;            // B*H*T*T dense attn output

    const size_t NQ = (size_t)B_ * H_ * T_ * HD_;          // 4194304
    char* w = (char*)d_ws;
    float* Vf      = (float*)w;  w += NQ * 4;
    float* ctx     = (float*)w;  w += (size_t)BT_ * C_ * 4;
    float* probs_c = (float*)w;  w += (size_t)ROWS_ * 32 * 4;
    int*   idx_c   = (int*)w;    w += (size_t)ROWS_ * 32 * 4;
    float* Qf      = (float*)w;  w += NQ * 4;
    float* Ktf     = (float*)w;  w += NQ * 4;              // [bh][d][2048]

    qkv_kernel<<<dim3(4, 64, 3), 256, 0, stream>>>(x, Wq, bq, Wk, bk, Wv, bv,
                                                   Qf, Ktf, Vf);
    fused_attn_topk<<<dim3(T_ / 8, B_ * H_), 256, 0, stream>>>(Qf, Ktf,
                                                               probs, probs_c, idx_c);
    context_kernel<<<dim3(ROWS_ / 4), 256, 0, stream>>>(Vf, probs_c, idx_c, ctx);
    wo_kernel<<<dim3(4, 64), 256, 0, stream>>>(ctx, Wo, bo, spikes);
    ln_kernel<<<dim3(BT_ / 4), 256, 0, stream>>>(spikes, gamma, beta);
    lif_kernel<<<dim3(32), 64, 0, stream>>>(spikes);
}

// Round 8
// 1237.945 us; speedup vs baseline: 1.1343x; 1.1343x over previous
//
#include <hip/hip_runtime.h>
#include <cstdint>
#include <math.h>

#define B_ 4
#define T_ 2048
#define C_ 512
#define H_ 8
#define HD_ 64
#define TOPK_ 32
#define ROWS_ (B_*H_*T_)   /* 65536 */
#define BT_ (B_*T_)        /* 8192 */

typedef __attribute__((ext_vector_type(2))) float f32x2;   // -> v_pk_fma_f32

// ---------------- QKV projection GEMM: (8192x512)@(512x512) ------------------------
// Q: [bh][tok][64] fp32. K: written TRANSPOSED as Kt[bh][d][2048] fp32 (so the fused
// scores kernel streams it fully coalesced). V: [bh][tok][64] fp32.
// Inner product uses packed f32x2 FMA (v_pk_fma_f32): 32 issues/k-step instead of 64.
__global__ __launch_bounds__(256) void qkv_kernel(
    const float* __restrict__ x,
    const float* __restrict__ Wq, const float* __restrict__ bq,
    const float* __restrict__ Wk, const float* __restrict__ bk,
    const float* __restrict__ Wv, const float* __restrict__ bv,
    float* __restrict__ Q, float* __restrict__ Kt, float* __restrict__ V)
{
    const int which = blockIdx.z;
    const float* W    = (which == 0) ? Wq : (which == 1) ? Wk : Wv;
    const float* bias = (which == 0) ? bq : (which == 1) ? bk : bv;

    const int m0 = blockIdx.y * 128;
    const int n0 = blockIdx.x * 128;
    __shared__ float As[16][128];   // [k][m] transposed
    __shared__ float Bs[16][128];   // [k][n]
    f32x2 acc2[8][4] = {};          // acc2[i][j][h] = C[row i][col j*2+h]
    const int tid = threadIdx.x;
    const int tx = tid & 15, ty = tid >> 4;

    for (int k0 = 0; k0 < C_; k0 += 16) {
        #pragma unroll
        for (int i = 0; i < 2; ++i) {
            int t = tid + i * 256;           // 0..511
            int m  = t >> 2;                 // 0..127
            int kq = (t & 3) << 2;           // 0,4,8,12
            float4 a4 = *(const float4*)(x + (size_t)(m0 + m) * C_ + k0 + kq);
            As[kq + 0][m] = a4.x; As[kq + 1][m] = a4.y;
            As[kq + 2][m] = a4.z; As[kq + 3][m] = a4.w;
            int kk2 = t >> 5;                // 0..15
            int nq  = (t & 31) << 2;         // 0..124
            *(float4*)&Bs[kk2][nq] = *(const float4*)(W + (size_t)(k0 + kk2) * C_ + n0 + nq);
        }
        __syncthreads();
        #pragma unroll
        for (int k = 0; k < 16; ++k) {
            float a[8];
            *(float4*)&a[0] = *(const float4*)&As[k][ty * 8];
            *(float4*)&a[4] = *(const float4*)&As[k][ty * 8 + 4];
            float4 bl = *(const float4*)&Bs[k][tx * 8];
            float4 bh = *(const float4*)&Bs[k][tx * 8 + 4];
            f32x2 b2[4];
            b2[0] = (f32x2){bl.x, bl.y}; b2[1] = (f32x2){bl.z, bl.w};
            b2[2] = (f32x2){bh.x, bh.y}; b2[3] = (f32x2){bh.z, bh.w};
            #pragma unroll
            for (int i = 0; i < 8; ++i) {
                f32x2 q2 = (f32x2){a[i], a[i]};
                #pragma unroll
                for (int j = 0; j < 4; ++j)
                    acc2[i][j] = __builtin_elementwise_fma(q2, b2[j], acc2[i][j]);
            }
        }
        __syncthreads();
    }

    const int bb = m0 >> 11;                 // batch index (m0 constant per block)
    const int t0 = (m0 & (T_ - 1)) + ty * 8; // token of acc row i=0

    if (which == 1) {
        // K transposed out: Kt[(bb*8+h)*64 + d][t]
        #pragma unroll
        for (int jj = 0; jj < 8; ++jj) {
            int n = n0 + tx * 8 + jj;
            int h = n >> 6, d = n & 63;
            float bv_ = bias[n];
            float* dst = Kt + (((size_t)(bb * H_ + h) * HD_ + d) << 11) + t0;
            float4 lo, hi;
            lo.x = acc2[0][jj >> 1][jj & 1] + bv_; lo.y = acc2[1][jj >> 1][jj & 1] + bv_;
            lo.z = acc2[2][jj >> 1][jj & 1] + bv_; lo.w = acc2[3][jj >> 1][jj & 1] + bv_;
            hi.x = acc2[4][jj >> 1][jj & 1] + bv_; hi.y = acc2[5][jj >> 1][jj & 1] + bv_;
            hi.z = acc2[6][jj >> 1][jj & 1] + bv_; hi.w = acc2[7][jj >> 1][jj & 1] + bv_;
            *(float4*)(dst)     = lo;
            *(float4*)(dst + 4) = hi;
        }
    } else {
        float* out = (which == 0) ? Q : V;
        #pragma unroll
        for (int i = 0; i < 8; ++i) {
            int t = t0 + i;
            #pragma unroll
            for (int j = 0; j < 8; j += 4) {
                int n = n0 + tx * 8 + j;
                int h = n >> 6, d = n & 63;
                int jp = j >> 1;
                float4 v4;
                v4.x = acc2[i][jp + 0][0] + bias[n + 0];
                v4.y = acc2[i][jp + 0][1] + bias[n + 1];
                v4.z = acc2[i][jp + 1][0] + bias[n + 2];
                v4.w = acc2[i][jp + 1][1] + bias[n + 3];
                *(float4*)(out + (((size_t)(bb * H_ + h) * T_ + t) << 6) + d) = v4;
            }
        }
    }
}

// ---------------- fused: fp32 scores + exact top-32 (linear-bucket select) ----------
// Block: 4 waves, 8 query rows x 2048 key cols. Scores in VGPRs as f32x2 pairs:
// acc2[r][j][h] = score[row r][col = wave*512 + (j>>1)*256 + (j&1)*2 + h + lane*4].
// Phase A uses v_pk_fma_f32 (packed fp32) -> half the FMA issue slots of scalar.
// Selection: one 256-bucket linear histogram (bucket ids packed into regs during the
// sweep), boundary bucket via suffix scan, exact (value desc, col asc) ranking of
// boundary candidates, canonical reorder -> bitwise deterministic output.
__global__ __launch_bounds__(256, 3) void fused_attn_topk(
    const float* __restrict__ Q, const float* __restrict__ Kt,
    float* __restrict__ S, float* __restrict__ probs_c, int* __restrict__ idx_c)
{
    const int tid  = threadIdx.x;
    const int wave = tid >> 6, lane = tid & 63;
    const int m0 = blockIdx.x * 8;
    const int bh = blockIdx.y;

    __shared__ float Qs[64][12];             // [d][row], padded to 48B stride
    __shared__ int   hist[8][257];           // padded: bank(r,b) = (r+b)&31
    __shared__ float wlo[4][8], whi[4][8];
    __shared__ float rowlo[8], rowinv[8];
    __shared__ int   bb_s[8], G_s[8], gcnt[8], cin[8];
    __shared__ float selv[8][32], selv2[8][32], candv[8][64];
    __shared__ int   seli[8][32], seli2[8][32], candc[8][64];

    // stage Q tile (8 tokens x 64 d) transposed; zero hist; init counters
    if (tid < 128) {
        int tok = tid >> 4;                  // 0..7
        int dq  = (tid & 15) << 2;           // 0,4,..,60
        float4 q4 = *(const float4*)(Q + (((size_t)bh * T_ + m0 + tok) << 6) + dq);
        Qs[dq + 0][tok] = q4.x; Qs[dq + 1][tok] = q4.y;
        Qs[dq + 2][tok] = q4.z; Qs[dq + 3][tok] = q4.w;
    }
    for (int idx = tid; idx < 8 * 257; idx += 256) ((int*)hist)[idx] = 0;
    if (tid < 8) { gcnt[tid] = 0; cin[tid] = 0; }
    __syncthreads();

    // ---- phase A: fp32 scores via packed FMA, register-resident ----
    f32x2 acc2[8][4];
    #pragma unroll
    for (int r = 0; r < 8; ++r)
        #pragma unroll
        for (int j = 0; j < 4; ++j) acc2[r][j] = (f32x2){0.f, 0.f};

    const float* ktp = Kt + ((size_t)bh * HD_ << 11) + wave * 512 + lane * 4;
    #pragma unroll 4
    for (int d = 0; d < 64; ++d) {
        float4 kv0 = *(const float4*)(ktp);
        float4 kv1 = *(const float4*)(ktp + 256);
        ktp += 2048;
        f32x2 k00 = (f32x2){kv0.x, kv0.y}, k01 = (f32x2){kv0.z, kv0.w};
        f32x2 k10 = (f32x2){kv1.x, kv1.y}, k11 = (f32x2){kv1.z, kv1.w};
        float qv[8];
        *(float4*)&qv[0] = *(const float4*)&Qs[d][0];
        *(float4*)&qv[4] = *(const float4*)&Qs[d][4];
        #pragma unroll
        for (int r = 0; r < 8; ++r) {
            f32x2 q2 = (f32x2){qv[r], qv[r]};
            acc2[r][0] = __builtin_elementwise_fma(q2, k00, acc2[r][0]);
            acc2[r][1] = __builtin_elementwise_fma(q2, k01, acc2[r][1]);
            acc2[r][2] = __builtin_elementwise_fma(q2, k10, acc2[r][2]);
            acc2[r][3] = __builtin_elementwise_fma(q2, k11, acc2[r][3]);
        }
    }
    #pragma unroll
    for (int r = 0; r < 8; ++r)
        #pragma unroll
        for (int j = 0; j < 4; ++j) acc2[r][j] *= 0.125f;   // exact pow2 scale

    // ---- per-row min/max (register shuffle reduce, no atomics) ----
    float mn[8], mx[8];
    #pragma unroll
    for (int r = 0; r < 8; ++r) {
        f32x2 mn2 = acc2[r][0], mx2 = acc2[r][0];
        #pragma unroll
        for (int j = 1; j < 4; ++j) {
            mn2 = __builtin_elementwise_min(mn2, acc2[r][j]);
            mx2 = __builtin_elementwise_max(mx2, acc2[r][j]);
        }
        mn[r] = fminf(mn2[0], mn2[1]);
        mx[r] = fmaxf(mx2[0], mx2[1]);
    }
    #pragma unroll
    for (int off = 32; off >= 1; off >>= 1) {
        #pragma unroll
        for (int r = 0; r < 8; ++r) {
            mn[r] = fminf(mn[r], __shfl_xor(mn[r], off));
            mx[r] = fmaxf(mx[r], __shfl_xor(mx[r], off));
        }
    }
    if (lane == 0) {
        #pragma unroll
        for (int r = 0; r < 8; ++r) { wlo[wave][r] = mn[r]; whi[wave][r] = mx[r]; }
    }
    __syncthreads();
    if (tid < 8) {
        float lo = wlo[0][tid], hi = whi[0][tid];
        #pragma unroll
        for (int w = 1; w < 4; ++w) {
            lo = fminf(lo, wlo[w][tid]);
            hi = fmaxf(hi, whi[w][tid]);
        }
        float range = hi - lo;
        rowlo[tid]  = lo;
        rowinv[tid] = (range > 0.f) ? (256.0f / range) : 0.f;
    }
    __syncthreads();

    // ---- one-pass 256-bucket histogram; pack bucket ids into registers ----
    float lo_r[8], inv_r[8];
    #pragma unroll
    for (int r = 0; r < 8; ++r) { lo_r[r] = rowlo[r]; inv_r[r] = rowinv[r]; }
    unsigned int bpack[16];                  // [r*2 + g]: buckets of cols g*256+{0..3}
    #pragma unroll
    for (int r = 0; r < 8; ++r) {
        #pragma unroll
        for (int g = 0; g < 2; ++g) {
            unsigned int pk = 0;
            #pragma unroll
            for (int jj = 0; jj < 2; ++jj) {
                #pragma unroll
                for (int h = 0; h < 2; ++h) {
                    float v = acc2[r][g * 2 + jj][h];
                    int b = (int)((v - lo_r[r]) * inv_r[r]);
                    b = b < 0 ? 0 : (b > 255 ? 255 : b);
                    pk |= (unsigned int)b << (8 * (jj * 2 + h));
                    atomicAdd(&hist[r][b], 1);
                }
            }
            bpack[r * 2 + g] = pk;
        }
    }
    __syncthreads();

    // ---- boundary bucket per row (suffix scan); wave w handles rows 2w,2w+1 ----
    #pragma unroll
    for (int rr = 0; rr < 2; ++rr) {
        const int row = wave * 2 + rr;
        int h0 = hist[row][lane * 4 + 0], h1 = hist[row][lane * 4 + 1];
        int h2 = hist[row][lane * 4 + 2], h3 = hist[row][lane * 4 + 3];
        int lsum = h0 + h1 + h2 + h3;
        int suf = lsum;
        #pragma unroll
        for (int off = 1; off < 64; off <<= 1) {
            int v = __shfl_down(suf, off);
            if (lane + off < 64) suf += v;
        }
        int a3 = suf - lsum;          // elems in strictly higher buckets
        int a2 = a3 + h3;
        int a1 = a2 + h2;
        int a0 = a1 + h1;
        if (a3 < TOPK_ && TOPK_ <= a3 + h3) { bb_s[row] = lane * 4 + 3; G_s[row] = a3; }
        if (a2 < TOPK_ && TOPK_ <= a2 + h2) { bb_s[row] = lane * 4 + 2; G_s[row] = a2; }
        if (a1 < TOPK_ && TOPK_ <= a1 + h1) { bb_s[row] = lane * 4 + 1; G_s[row] = a1; }
        if (a0 < TOPK_ && TOPK_ <= a0 + h0) { bb_s[row] = lane * 4 + 0; G_s[row] = a0; }
    }
    __syncthreads();

    // ---- collect: definite winners (b > boundary) + boundary candidates ----
    int bb_r[8];
    #pragma unroll
    for (int r = 0; r < 8; ++r) bb_r[r] = bb_s[r];
    const int colb = wave * 512 + lane * 4;
    #pragma unroll
    for (int r = 0; r < 8; ++r) {
        #pragma unroll
        for (int g = 0; g < 2; ++g) {
            unsigned int pk = bpack[r * 2 + g];
            #pragma unroll
            for (int jj = 0; jj < 2; ++jj) {
                #pragma unroll
                for (int h = 0; h < 2; ++h) {
                    int b = (int)((pk >> (8 * (jj * 2 + h))) & 255u);
                    int col = colb + (g << 8) + (jj << 1) + h;
                    float v = acc2[r][g * 2 + jj][h];
                    if (b > bb_r[r]) {
                        int p = atomicAdd(&gcnt[r], 1);
                        selv[r][p] = v;
                        seli[r][p] = col;
                    } else if (b == bb_r[r]) {
                        int q = atomicAdd(&cin[r], 1);
                        if (q < 64) { candv[r][q] = v; candc[r][q] = col; }
                    }
                }
            }
        }
    }
    __syncthreads();

    // ---- exact rank of boundary candidates (value desc, col asc) ----
    // Deterministic: rank is a function of the candidate SET, not slot order.
    #pragma unroll
    for (int base = 0; base < 512; base += 256) {
        int idx = base + tid;
        int r = idx >> 6, j = idx & 63;
        int cnt = cin[r]; if (cnt > 64) cnt = 64;
        int G = G_s[r], need = TOPK_ - G;
        if (j < cnt) {
            float v = candv[r][j]; int c = candc[r][j];
            int rank = 0;
            for (int s = 0; s < cnt; ++s) {
                float vo = candv[r][s]; int co = candc[r][s];
                rank += (vo > v) || (vo == v && co < c);
            }
            if (rank < need) { selv[r][G + rank] = v; seli[r][G + rank] = c; }
        }
    }
    __syncthreads();

    // ---- canonical rank-reorder of the 32 (value desc, col asc) ----
    {
        int row = tid >> 5, slot = tid & 31;
        float v = selv[row][slot];
        int   c = seli[row][slot];
        int rank = 0;
        #pragma unroll
        for (int s = 0; s < 32; ++s) {
            float vo = selv[row][s]; int co = seli[row][s];
            rank += (vo > v) || (vo == v && co < c);
        }
        selv2[row][rank] = v;
        seli2[row][rank] = c;
    }
    __syncthreads();

    // ---- softmax over 32 per row + compact outputs ----
    {
        int row = tid >> 5, slot = tid & 31;
        float v = selv2[row][slot];
        float mxv = v;
        #pragma unroll
        for (int off = 16; off >= 1; off >>= 1) mxv = fmaxf(mxv, __shfl_xor(mxv, off, 32));
        float ex = expf(v - mxv);
        float sm = ex;
        #pragma unroll
        for (int off = 16; off >= 1; off >>= 1) sm += __shfl_xor(sm, off, 32);
        float p = ex / sm;
        selv2[row][slot] = p;
        size_t grow = (size_t)(bh * T_ + m0 + row) * 32 + slot;
        probs_c[grow] = p;
        idx_c[grow]   = seli2[row][slot];
    }
    __syncthreads();

    // ---- dense output: zero 8x2048 then scatter 8x32 probs ----
    float* Sb = S + (size_t)bh * T_ * T_ + (size_t)m0 * T_;
    float4 z4 = {0.f, 0.f, 0.f, 0.f};
    #pragma unroll
    for (int i = 0; i < 16; ++i) ((float4*)Sb)[tid + i * 256] = z4;
    __syncthreads();
    {
        int row = tid >> 5, slot = tid & 31;
        Sb[(size_t)row * T_ + seli2[row][slot]] = selv2[row][slot];
    }
}

// ---------------- sparse context: ctx[b,t,h*64+d] = sum_j p_j * V[bh, idx_j, d] ----
__global__ __launch_bounds__(256) void context_kernel(
    const float* __restrict__ V, const float* __restrict__ probs_c,
    const int* __restrict__ idx_c, float* __restrict__ ctx)
{
    const int wid = blockIdx.x * 4 + (threadIdx.x >> 6);
    const int lane = threadIdx.x & 63;
    const int bh = wid >> 11, t = wid & (T_ - 1);
    const float* Vb = V + ((size_t)bh * T_ << 6);
    const float* pr = probs_c + (size_t)wid * 32;
    const int* ir = idx_c + (size_t)wid * 32;
    float acc = 0.f;
    #pragma unroll 8
    for (int j = 0; j < 32; ++j) {
        float p = pr[j];
        int ix = ir[j];
        acc += p * Vb[((size_t)ix << 6) + lane];
    }
    const int b = bh >> 3, h = bh & 7;
    ctx[(size_t)(b * T_ + t) * C_ + h * 64 + lane] = acc;
}

// ---------------- Wo GEMM + bias -> analog (row-major), packed FMA ------------------
__global__ __launch_bounds__(256) void wo_kernel(
    const float* __restrict__ A, const float* __restrict__ W,
    const float* __restrict__ bias, float* __restrict__ out)
{
    const int m0 = blockIdx.y * 128;
    const int n0 = blockIdx.x * 128;
    __shared__ float As[16][128];
    __shared__ float Bs[16][128];
    f32x2 acc2[8][4] = {};
    const int tid = threadIdx.x;
    const int tx = tid & 15, ty = tid >> 4;

    for (int k0 = 0; k0 < C_; k0 += 16) {
        #pragma unroll
        for (int i = 0; i < 2; ++i) {
            int t = tid + i * 256;
            int m  = t >> 2;
            int kq = (t & 3) << 2;
            float4 a4 = *(const float4*)(A + (size_t)(m0 + m) * C_ + k0 + kq);
            As[kq + 0][m] = a4.x; As[kq + 1][m] = a4.y;
            As[kq + 2][m] = a4.z; As[kq + 3][m] = a4.w;
            int kk2 = t >> 5;
            int nq  = (t & 31) << 2;
            *(float4*)&Bs[kk2][nq] = *(const float4*)(W + (size_t)(k0 + kk2) * C_ + n0 + nq);
        }
        __syncthreads();
        #pragma unroll
        for (int k = 0; k < 16; ++k) {
            float a[8];
            *(float4*)&a[0] = *(const float4*)&As[k][ty * 8];
            *(float4*)&a[4] = *(const float4*)&As[k][ty * 8 + 4];
            float4 bl = *(const float4*)&Bs[k][tx * 8];
            float4 bh = *(const float4*)&Bs[k][tx * 8 + 4];
            f32x2 b2[4];
            b2[0] = (f32x2){bl.x, bl.y}; b2[1] = (f32x2){bl.z, bl.w};
            b2[2] = (f32x2){bh.x, bh.y}; b2[3] = (f32x2){bh.z, bh.w};
            #pragma unroll
            for (int i = 0; i < 8; ++i) {
                f32x2 q2 = (f32x2){a[i], a[i]};
                #pragma unroll
                for (int j = 0; j < 4; ++j)
                    acc2[i][j] = __builtin_elementwise_fma(q2, b2[j], acc2[i][j]);
            }
        }
        __syncthreads();
    }
    #pragma unroll
    for (int i = 0; i < 8; ++i) {
        int r = m0 + ty * 8 + i;
        #pragma unroll
        for (int j = 0; j < 8; j += 4) {
            int n = n0 + tx * 8 + j;
            int jp = j >> 1;
            float4 v4;
            v4.x = acc2[i][jp + 0][0] + bias[n + 0];
            v4.y = acc2[i][jp + 0][1] + bias[n + 1];
            v4.z = acc2[i][jp + 1][0] + bias[n + 2];
            v4.w = acc2[i][jp + 1][1] + bias[n + 3];
            *(float4*)(out + (size_t)r * C_ + n) = v4;
        }
    }
}

// ---------------- LayerNorm in place: one wave per row of 512 ----------------------
__global__ __launch_bounds__(256) void ln_kernel(
    float* __restrict__ a, const float* __restrict__ gamma, const float* __restrict__ beta)
{
    const int row = blockIdx.x * 4 + (threadIdx.x >> 6);
    const int lane = threadIdx.x & 63;
    float* ar = a + (size_t)row * C_;
    float x[8];
    *(float4*)&x[0] = *(const float4*)(ar + lane * 8);
    *(float4*)&x[4] = *(const float4*)(ar + lane * 8 + 4);
    float s = 0.f;
    #pragma unroll
    for (int i = 0; i < 8; ++i) s += x[i];
    #pragma unroll
    for (int off = 32; off >= 1; off >>= 1) s += __shfl_xor(s, off);
    float mu = s * (1.0f / C_);
    float vs = 0.f;
    #pragma unroll
    for (int i = 0; i < 8; ++i) { float d = x[i] - mu; vs += d * d; }
    #pragma unroll
    for (int off = 32; off >= 1; off >>= 1) vs += __shfl_xor(vs, off);
    float rs = rsqrtf(vs * (1.0f / C_) + 1e-5f);
    float g[8], bt[8];
    *(float4*)&g[0]  = *(const float4*)(gamma + lane * 8);
    *(float4*)&g[4]  = *(const float4*)(gamma + lane * 8 + 4);
    *(float4*)&bt[0] = *(const float4*)(beta + lane * 8);
    *(float4*)&bt[4] = *(const float4*)(beta + lane * 8 + 4);
    #pragma unroll
    for (int i = 0; i < 8; ++i) x[i] = (x[i] - mu) * rs * g[i] + bt[i];
    *(float4*)(ar + lane * 8)     = *(float4*)&x[0];
    *(float4*)(ar + lane * 8 + 4) = *(float4*)&x[4];
}

// ---------------- adaptive LIF scan, in place (analog -> spikes) -------------------
#define LIF_BATCH 32
__global__ __launch_bounds__(64) void lif_kernel(float* __restrict__ a)
{
    const int wid = blockIdx.x;                 // 0..31
    const int b = wid >> 3;
    const int c = ((wid & 7) << 6) | threadIdx.x;
    float* base = a + (size_t)b * T_ * C_ + c;

    float xb[2][LIF_BATCH];
    #pragma unroll
    for (int j = 0; j < LIF_BATCH; ++j)
        xb[0][j] = base[(size_t)j * C_];

    float vmem = 0.f, adapt = 0.f;
    #pragma unroll 1
    for (int t0 = 0; t0 < T_; t0 += LIF_BATCH) {
        const int cur = (t0 / LIF_BATCH) & 1;
        if (t0 + LIF_BATCH < T_) {
            #pragma unroll
            for (int j = 0; j < LIF_BATCH; ++j)
                xb[cur ^ 1][j] = base[(size_t)(t0 + LIF_BATCH + j) * C_];
        }
        #pragma unroll
        for (int j = 0; j < LIF_BATCH; ++j) {
            float x = xb[cur][j];
            vmem = fmaf(0.9f, vmem, x);
            float th = fmaf(0.1f, adapt, 1.0f);
            float s = (vmem - th) > 0.f ? 1.f : 0.f;
            vmem -= s * th;
            adapt = fmaf(0.9f, adapt, s);
            xb[cur][j] = s;
        }
        #pragma unroll
        for (int j = 0; j < LIF_BATCH; ++j)
            base[(size_t)(t0 + j) * C_] = xb[cur][j];
    }
}

extern "C" void kernel_launch(void* const* d_in, const int* in_sizes, int n_in,
                              void* d_out, int out_size, void* d_ws, size_t ws_size,
                              hipStream_t stream)
{
    const float* x     = (const float*)d_in[0];
    const float* Wq    = (const float*)d_in[1];
    const float* bq    = (const float*)d_in[2];
    const float* Wk    = (const float*)d_in[3];
    const float* bk    = (const float*)d_in[4];
    const float* Wv    = (const float*)d_in[5];
    const float* bv    = (const float*)d_in[6];
    const float* Wo    = (const float*)d_in[7];
    const float* bo    = (const float*)d_in[8];
    const float* gamma = (const float*)d_in[9];
    const float* beta  = (const float*)d_in[10];

    float* out    = (float*)d_out;
    float* spikes = out;                                   // B*T*C (also analog scratch)
    float* probs  = out + (size_t)B_ * T_ * C_;            // B*H*T*T dense attn output

    const size_t NQ = (size_t)B_ * H_ * T_ * HD_;          // 4194304
    char* w = (char*)d_ws;
    float* Vf      = (float*)w;  w += NQ * 4;
    float* ctx     = (float*)w;  w += (size_t)BT_ * C_ * 4;
    float* probs_c = (float*)w;  w += (size_t)ROWS_ * 32 * 4;
    int*   idx_c   = (int*)w;    w += (size_t)ROWS_ * 32 * 4;
    float* Qf      = (float*)w;  w += NQ * 4;
    float* Ktf     = (float*)w;  w += NQ * 4;              // [bh][d][2048]

    qkv_kernel<<<dim3(4, 64, 3), 256, 0, stream>>>(x, Wq, bq, Wk, bk, Wv, bv,
                                                   Qf, Ktf, Vf);
    fused_attn_topk<<<dim3(T_ / 8, B_ * H_), 256, 0, stream>>>(Qf, Ktf,
                                                               probs, probs_c, idx_c);
    context_kernel<<<dim3(ROWS_ / 4), 256, 0, stream>>>(Vf, probs_c, idx_c, ctx);
    wo_kernel<<<dim3(4, 64), 256, 0, stream>>>(ctx, Wo, bo, spikes);
    ln_kernel<<<dim3(BT_ / 4), 256, 0, stream>>>(spikes, gamma, beta);
    lif_kernel<<<dim3(32), 64, 0, stream>>>(spikes);
}